// Round 8
// baseline (231.034 us; speedup 1.0000x reference)
//
#include <hip/hip_runtime.h>

// SwitchTransformersLoadBalancer:
//   x: (B=64, C=8, H=256, W=256) f32, accumulator: (256, 8) f32
//   out = one_hot(argmax_c (x_c - log(mean(acc[:,c]))))   [proved R0/R1, absmax 0]
// R10: wave-per-channel LDS exchange -- make all global traffic CONTIGUOUS.
//   Evidence: every per-thread-all-channels structure (R2-R9, 16 strided 1-2KB
//   chunks per wave) serviced at 2.3-3.3 TB/s; harness fills (contiguous
//   writes) hit 6.7 TB/s in the same captures. Run length, not occupancy, is
//   the lever (R3/R8 4-group > R9/R5 2-group > R6 1-group).
//   Structure: 512-thr blocks (8 waves), wave w owns channel w. Per 1024-px
//   tile: wave w nt-loads 4 KB contiguous from plane w -> LDS; all threads
//   argmax from LDS (stride-1 reads); wave w nt-stores 4 KB contiguous
//   one-hot to plane w. Double-buffered (X 64KB + I 8KB = 72 KB, 2 blk/CU),
//   next-tile loads issued before compute+store so they hide. 1 barrier/tile.
//   Lognorm: barrier-free per-wave f64 butterfly (bit-identical, kept).

#define P4 256    // float4 per tile per plane (1024 floats = 4 KB)

typedef float fvec4 __attribute__((ext_vector_type(4)));
typedef unsigned int uvec4 __attribute__((ext_vector_type(4)));

__global__ __launch_bounds__(512, 4) void fused_route_kernel(
        const float* __restrict__ x,
        const float* __restrict__ acc,
        float* __restrict__ out) {
    const int t    = threadIdx.x;     // 0..511
    const int w    = t >> 6;          // wave id == owned channel
    const int lane = t & 63;

    const int b      = blockIdx.x >> 3;        // batch (8 blocks per batch)
    const int chunk0 = (blockIdx.x & 7) << 3;  // first of this block's 8 chunks

    // this wave's plane bases (float4 units; 16384 f4 per plane)
    const fvec4* xp = (const fvec4*)x   + ((size_t)(b * 8 + w) << 14);
    fvec4*       op = (fvec4*)out       + ((size_t)(b * 8 + w) << 14);

    __shared__ __align__(16) float        X[2][8][1024];  // staged x tiles
    __shared__ __align__(16) unsigned int I[2][1024];     // argmax indices

    // ---- acc loads first, then tile-0 x loads: both in flight through ln ----
    const fvec4* accv = (const fvec4*)acc;     // 512 fvec4 (8 KB), L2-resident
    fvec4 a0 = accv[4 * lane + 0];
    fvec4 a1 = accv[4 * lane + 1];
    fvec4 a2 = accv[4 * lane + 2];
    fvec4 a3 = accv[4 * lane + 3];
    fvec4 b0 = accv[256 + 4 * lane + 0];
    fvec4 b1 = accv[256 + 4 * lane + 1];
    fvec4 b2 = accv[256 + 4 * lane + 2];
    fvec4 b3 = accv[256 + 4 * lane + 3];

    fvec4 r0, r1, r2, r3;
    {
        const fvec4* src = xp + chunk0 * P4;   // 4 KB contiguous per wave
        r0 = __builtin_nontemporal_load(src +       lane);
        r1 = __builtin_nontemporal_load(src +  64 + lane);
        r2 = __builtin_nontemporal_load(src + 128 + lane);
        r3 = __builtin_nontemporal_load(src + 192 + lane);
    }

    // ---- per-lane partial sums (4 rows, all 8 channels), f64 ----
    double s[8];
    s[0] = (double)a0.x + (double)a2.x + (double)b0.x + (double)b2.x;
    s[1] = (double)a0.y + (double)a2.y + (double)b0.y + (double)b2.y;
    s[2] = (double)a0.z + (double)a2.z + (double)b0.z + (double)b2.z;
    s[3] = (double)a0.w + (double)a2.w + (double)b0.w + (double)b2.w;
    s[4] = (double)a1.x + (double)a3.x + (double)b1.x + (double)b3.x;
    s[5] = (double)a1.y + (double)a3.y + (double)b1.y + (double)b3.y;
    s[6] = (double)a1.z + (double)a3.z + (double)b1.z + (double)b3.z;
    s[7] = (double)a1.w + (double)a3.w + (double)b1.w + (double)b3.w;

    #pragma unroll
    for (int m = 1; m < 64; m <<= 1) {
        #pragma unroll
        for (int c = 0; c < 8; ++c) s[c] += __shfl_xor(s[c], m, 64);
    }

    double ln[8];
    #pragma unroll
    for (int c = 0; c < 8; ++c) ln[c] = log(s[c] * (1.0 / 256.0));

    // ---- stage tile 0 ----
    {
        fvec4* Xr = (fvec4*)X[0][w];
        Xr[lane] = r0; Xr[64 + lane] = r1; Xr[128 + lane] = r2; Xr[192 + lane] = r3;
    }
    __syncthreads();

    // ---- main loop: 8 tiles, double-buffered, 1 barrier per tile ----
    for (int j = 0; j < 8; ++j) {
        const int cur = j & 1;
        const int nxt = cur ^ 1;

        // issue next tile's contiguous loads (latency hides under compute+store)
        if (j < 7) {
            const fvec4* src = xp + (chunk0 + j + 1) * P4;
            r0 = __builtin_nontemporal_load(src +       lane);
            r1 = __builtin_nontemporal_load(src +  64 + lane);
            r2 = __builtin_nontemporal_load(src + 128 + lane);
            r3 = __builtin_nontemporal_load(src + 192 + lane);
        }

        // compute tile j: pixels t and t+512 (stride-1 LDS reads, no conflicts)
        {
            float xa[8], xc[8];
            #pragma unroll
            for (int c = 0; c < 8; ++c) {
                xa[c] = X[cur][c][t];
                xc[c] = X[cur][c][t + 512];
            }
            double bestA = (double)xa[0] - ln[0]; int ia = 0;
            double bestC = (double)xc[0] - ln[0]; int ic = 0;
            #pragma unroll
            for (int c = 1; c < 8; ++c) {
                double d;
                d = (double)xa[c] - ln[c]; if (d > bestA) { bestA = d; ia = c; }
                d = (double)xc[c] - ln[c]; if (d > bestC) { bestC = d; ic = c; }
            }
            I[cur][t]       = (unsigned)ia;
            I[cur][t + 512] = (unsigned)ic;
        }

        // store tile j-1: wave w writes 4 KB contiguous one-hot to plane w
        if (j >= 1) {
            const int prv    = cur ^ 1;
            const int pchunk = chunk0 + j - 1;
            const uvec4* Iv  = (const uvec4*)I[prv];
            #pragma unroll
            for (int i = 0; i < 4; ++i) {
                uvec4 q = Iv[i * 64 + lane];
                fvec4 o;
                o.x = (q.x == (unsigned)w) ? 1.0f : 0.0f;
                o.y = (q.y == (unsigned)w) ? 1.0f : 0.0f;
                o.z = (q.z == (unsigned)w) ? 1.0f : 0.0f;
                o.w = (q.w == (unsigned)w) ? 1.0f : 0.0f;
                __builtin_nontemporal_store(o, op + pchunk * P4 + i * 64 + lane);
            }
        }

        // land the staged registers into the next buffer
        if (j < 7) {
            fvec4* Xr = (fvec4*)X[nxt][w];
            Xr[lane] = r0; Xr[64 + lane] = r1; Xr[128 + lane] = r2; Xr[192 + lane] = r3;
        }
        __syncthreads();
    }

    // ---- epilogue: store tile 7 (indices in I[1]) ----
    {
        const int pchunk = chunk0 + 7;
        const uvec4* Iv  = (const uvec4*)I[1];
        #pragma unroll
        for (int i = 0; i < 4; ++i) {
            uvec4 q = Iv[i * 64 + lane];
            fvec4 o;
            o.x = (q.x == (unsigned)w) ? 1.0f : 0.0f;
            o.y = (q.y == (unsigned)w) ? 1.0f : 0.0f;
            o.z = (q.z == (unsigned)w) ? 1.0f : 0.0f;
            o.w = (q.w == (unsigned)w) ? 1.0f : 0.0f;
            __builtin_nontemporal_store(o, op + pchunk * P4 + i * 64 + lane);
        }
    }
}

extern "C" void kernel_launch(void* const* d_in, const int* in_sizes, int n_in,
                              void* d_out, int out_size, void* d_ws, size_t ws_size,
                              hipStream_t stream) {
    const float* x   = (const float*)d_in[0];   // (64, 8, 256, 256)
    const float* acc = (const float*)d_in[1];   // (256, 8)
    float*       out = (float*)d_out;           // (64, 8, 256, 256)
    (void)d_ws; (void)ws_size;

    // 4096 tiles of 1024 pixels; 8 tiles per block -> 512 blocks x 512 threads
    // (= exactly 2 blocks/CU, LDS-capped at 72 KB/block).
    fused_route_kernel<<<512, 512, 0, stream>>>(x, acc, out);
}